// Round 4
// baseline (28.860 us; speedup 1.0000x reference)
//
#include <hip/hip_runtime.h>

// InvariantPolynomial: out = sum_e xl[oi[e]] * xr[e] * f(|pos_e|)
// f depends only on d=|pos| (sh[:, :1] == 1); tabulated in a 2048-entry LUT
// over [0,5] (f==0 in fp32 beyond d=5), linear interp (rel err ~1e-4 << 2e-2 tol).
//
// R4: tiled edge kernel. Block owns 1024 edges: pos staged LDS via coalesced
// float4 (minimum line-requests), xr float4 / oi int4 (16B/lane), 4 edges per
// thread from LDS (static indexing, 48B stride -> <=2-way bank alias = free).
// No __threadfence anywhere (R2 lesson: device-scope fence per block = +40us).
//
// ws layout: [0,8KB) float LUT; then double partials[NBLK]. ~24KB total.

#define TN    2048
#define DMAXF 5.0f
#define TPB   256
#define TILE  1024   // edges per block

// 1/sqrt(E[silu(z)^2]), z~N(0,1); matched reference exactly (absmax 0.0 R1-R3).
__device__ __constant__ float kSiluCst = 1.6765581f;

__global__ __launch_bounds__(256) void build_lut_kernel(
    const float* __restrict__ W1, const float* __restrict__ W2,
    float* __restrict__ table)
{
    // 32 lanes per LUT entry: lane k in [0,30) computes hidden unit k.
    int t = blockIdx.x * 256 + threadIdx.x;
    int entry = t >> 5;
    int k = t & 31;
    int kk = (k < 30) ? k : 29;

    float d  = (float)entry * (DMAXF / (float)TN);
    float t6 = 6.0f * d;                      // centers at t6 = 1..20 (step=1/6)
    const float w1scale = 1.0f / (1.12f * sqrtf(20.0f));

    float a = 0.0f;
    #pragma unroll
    for (int j = 0; j < 20; ++j) {
        float df = t6 - (float)(j + 1);
        float e  = __expf(-df * df);
        a = fmaf(e * w1scale, W1[j * 30 + kk], a);
    }
    float s = a / (1.0f + __expf(-a));        // silu

    float w2s = 0.0f;
    #pragma unroll
    for (int c = 0; c < 5; ++c) w2s += W2[kk * 5 + c];

    float contrib = (k < 30) ? s * w2s * (kSiluCst / sqrtf(30.0f)) : 0.0f;

    #pragma unroll
    for (int m = 16; m > 0; m >>= 1) contrib += __shfl_xor(contrib, m, 32);

    if (k == 0 && entry < TN) table[entry] = contrib;
}

__global__ __launch_bounds__(TPB) void edge_sum_kernel(
    const float* __restrict__ pos, const float* __restrict__ xr,
    const float* __restrict__ xl, const int* __restrict__ oi,
    const float* __restrict__ table, double* __restrict__ partials, int E)
{
    __shared__ float lut[TN];            // 8KB
    __shared__ float lpos[3 * TILE];     // 12KB
    __shared__ double swv[TPB / 64];

    const int tid = threadIdx.x;
    const long tile0 = (long)blockIdx.x * TILE;

    {   // stage 8KB LUT: 2 float4 per thread (coalesced, L2/L3-resident source)
        const float4* t4 = (const float4*)table;
        float4* l4 = (float4*)lut;
        l4[tid]       = t4[tid];
        l4[tid + TPB] = t4[tid + TPB];
    }
    {   // stage 12KB pos tile: 3 coalesced float4 per thread
        const long  gbase4 = (tile0 * 3) / 4;        // tile0*3 % 4 == 0 (TILE%4==0)
        const long  lim4   = (3L * E) / 4;           // full float4s in pos
        const float4* g4 = (const float4*)pos;
        float4* l4 = (float4*)lpos;
        #pragma unroll
        for (int i = 0; i < 3; ++i) {
            int li = tid + i * TPB;                  // 0..767
            long gi = gbase4 + li;
            if (gi < lim4) l4[li] = g4[gi];
        }
        // scalar tail (only if 3E not multiple of 4; absent for E=2M)
        long tail = lim4 * 4 + tid;
        if (tail < 3L * E && tail >= tile0 * 3 && tail < tile0 * 3 + 3 * TILE)
            lpos[tail - tile0 * 3] = pos[tail];
    }
    __syncthreads();

    const float scale = (float)TN / DMAXF;
    const float umax  = (float)(TN - 1) - 1e-3f;

    const int rem = (int)min((long)TILE, (long)E - tile0);  // valid edges in tile
    const int e0  = tid * 4;                                 // this thread's first edge
    double acc = 0.0;

    if (e0 + 4 <= rem) {
        // vector path: 4 edges
        const float4* lp4 = (const float4*)lpos;
        float4 a = lp4[3 * tid + 0];
        float4 b = lp4[3 * tid + 1];
        float4 c = lp4[3 * tid + 2];
        float4 xv = ((const float4*)(xr + tile0))[tid];
        int4   ov = ((const int4*)(oi + tile0))[tid];

        float px[4] = {a.x, a.w, b.z, c.y};
        float py[4] = {a.y, b.x, b.w, c.z};
        float pz[4] = {a.z, b.y, c.x, c.w};
        float xrv[4] = {xv.x, xv.y, xv.z, xv.w};
        float xlv[4];
        xlv[0] = xl[ov.x]; xlv[1] = xl[ov.y]; xlv[2] = xl[ov.z]; xlv[3] = xl[ov.w];

        float fsum = 0.0f;
        #pragma unroll
        for (int j = 0; j < 4; ++j) {
            float d  = sqrtf(fmaf(px[j], px[j], fmaf(py[j], py[j], pz[j] * pz[j])));
            float u  = fminf(d * scale, umax);
            int   i0 = (int)u;
            float fr = u - (float)i0;
            float f  = fmaf(fr, lut[i0 + 1] - lut[i0], lut[i0]);
            fsum = fmaf(f * xrv[j], xlv[j], fsum);
        }
        acc = (double)fsum;
    } else if (e0 < rem) {
        // guarded scalar path (tail block only)
        float fsum = 0.0f;
        for (int j = 0; j < 4 && e0 + j < rem; ++j) {
            int le = e0 + j;
            float x = lpos[3 * le], y = lpos[3 * le + 1], z = lpos[3 * le + 2];
            float d  = sqrtf(fmaf(x, x, fmaf(y, y, z * z)));
            float u  = fminf(d * scale, umax);
            int   i0 = (int)u;
            float fr = u - (float)i0;
            float f  = fmaf(fr, lut[i0 + 1] - lut[i0], lut[i0]);
            long  ge = tile0 + le;
            fsum = fmaf(f * xr[ge], xl[oi[ge]], fsum);
        }
        acc = (double)fsum;
    }

    // deterministic block reduction (wave shfl + LDS across 4 waves)
    #pragma unroll
    for (int off = 32; off > 0; off >>= 1) acc += __shfl_down(acc, off);
    int lane = tid & 63, wv = tid >> 6;
    if (lane == 0) swv[wv] = acc;
    __syncthreads();
    if (tid == 0)
        partials[blockIdx.x] = (swv[0] + swv[1]) + (swv[2] + swv[3]);
}

__global__ __launch_bounds__(256) void final_reduce_kernel(
    const double* __restrict__ partials, int n, float* __restrict__ out)
{
    __shared__ double sm[256];
    double a = 0.0;
    for (int i = threadIdx.x; i < n; i += 256) a += partials[i];
    sm[threadIdx.x] = a;
    __syncthreads();
    #pragma unroll
    for (int s = 128; s > 0; s >>= 1) {
        if (threadIdx.x < (unsigned)s) sm[threadIdx.x] += sm[threadIdx.x + s];
        __syncthreads();
    }
    if (threadIdx.x == 0) out[0] = (float)sm[0];
}

extern "C" void kernel_launch(void* const* d_in, const int* in_sizes, int n_in,
                              void* d_out, int out_size, void* d_ws, size_t ws_size,
                              hipStream_t stream) {
    const float* pos = (const float*)d_in[0];   // [E,3]
    const float* xr  = (const float*)d_in[1];   // [E,1]
    const float* xl  = (const float*)d_in[2];   // [N,1]
    const float* W1  = (const float*)d_in[3];   // [20,30]
    const float* W2  = (const float*)d_in[4];   // [30,5]
    const int*   oi  = (const int*)d_in[5];     // [E]
    float* out = (float*)d_out;

    int E = in_sizes[1];
    int nblk = (E + TILE - 1) / TILE;           // 1954 for E=2M

    float*  table    = (float*)d_ws;
    double* partials = (double*)((char*)d_ws + (size_t)TN * sizeof(float));

    hipLaunchKernelGGL(build_lut_kernel, dim3((TN * 32) / 256), dim3(256), 0, stream,
                       W1, W2, table);
    hipLaunchKernelGGL(edge_sum_kernel, dim3(nblk), dim3(TPB), 0, stream,
                       pos, xr, xl, oi, table, partials, E);
    hipLaunchKernelGGL(final_reduce_kernel, dim3(1), dim3(256), 0, stream,
                       partials, nblk, out);
}